// Round 10
// baseline (220.506 us; speedup 1.0000x reference)
//
#include <hip/hip_runtime.h>
#include <hip/hip_bf16.h>
#include <stdint.h>

#define BATCH 4096
#define TLEN  1024
#define NF_IT 171        // fwd k3 iters: steps 1..513 -> alpha_513
#define NB_IT 170        // bwd: 169 tailed k3 iters + 1 tail-less peel -> beta_513
#define MSTR  72         // pre-kernel LDS matrix row stride (elements)
#define PSTR  72         // main-kernel alpha row stride (elements)

typedef short bf16x8 __attribute__((ext_vector_type(8)));
typedef float f32x4  __attribute__((ext_vector_type(4)));

#define MFMA(a,b,c) __builtin_amdgcn_mfma_f32_16x16x32_bf16(a,b,c,0,0,0)

// ---- ws layout (bytes) ----
#define WS_C3T 0          // bf16 C3t[4][64][64]: C3t[m][y][x] = C3_m[x][y] (fwd A, transposed)
#define WS_C3P 32768      // bf16 C3p[4][64][64]: plain (bwd A) -> ends 65536
#define WS_PE  65536      // float pE[2][64]
#define WS_PIV 66048      // float piv[64] -> ends 66304

// ---- pre-kernel LDS (bytes) ----
#define PT_T   0
#define PT_VT0 9216
#define PT_VTD 18432
#define PT_WP0 27648
#define PT_WPD 36864
#define PT_PE  46080
#define PT_PIV 46592
#define PRE_SZ 46848

// ---------------------------------------------------------------------------
// Pre-kernel (1 wg x 256): k3 multilinear bases
//   C3_{a,b} = T Dh(a) T Dh(b) T,  Dh(0)=diag(e0), Dh(1)=diag(e1-e0)
// via V_x = Dh(x)*T (transposed), W_x = T*V_x (plain), C3 = W_a*V_b (MFMA).
// Stores fwd-transposed + bwd-plain, plus pE/piv; zeroes out.
// ---------------------------------------------------------------------------
__global__ __launch_bounds__(256) void hmm_pre(
    const float* __restrict__ Tmat, const float* __restrict__ Emat,
    const float* __restrict__ Pi, unsigned char* __restrict__ ws,
    float* __restrict__ out)
{
    __shared__ __align__(16) unsigned char SM[PRE_SZ];
    const int tid = threadIdx.x;
    const int wv  = tid >> 6;
    const int lane = tid & 63;
    const int lr  = lane & 15;
    const int g   = lane >> 4;
    float* pE  = (float*)(SM + PT_PE);
    const f32x4 zero = {0.f, 0.f, 0.f, 0.f};

    // phase 0: emission + pi softmax; export pE/piv; zero out
    if (tid < 64) {
        const float e0 = Emat[tid*2+0], e1 = Emat[tid*2+1];
        const float em = fmaxf(e0, e1);
        const float p0 = __expf(e0-em), p1 = __expf(e1-em);
        const float ez = 1.0f / (p0 + p1);
        pE[tid]      = p0 * ez;
        pE[64 + tid] = p1 * ez;
        ((float*)(ws + WS_PE))[tid]      = p0 * ez;
        ((float*)(ws + WS_PE))[64 + tid] = p1 * ez;
        float v = Pi[tid];
        float mx = v;
        #pragma unroll
        for (int d = 1; d < 64; d <<= 1) mx = fmaxf(mx, __shfl_xor(mx, d));
        const float e = __expf(v - mx);
        float z = e;
        #pragma unroll
        for (int d = 1; d < 64; d <<= 1) z += __shfl_xor(z, d);
        ((float*)(ws + WS_PIV))[tid] = e / z;
        if (tid == 0) *out = 0.f;
    }
    __syncthreads();

    // phase 1: row-softmax of T; T plain + V0/VD transposed
    {
        const int r  = tid >> 2;
        const int q4 = tid & 3;
        float v[16];
        #pragma unroll
        for (int q = 0; q < 4; q++) {
            const float4 t4 = *(const float4*)(Tmat + r*64 + q4*16 + q*4);
            v[q*4+0]=t4.x; v[q*4+1]=t4.y; v[q*4+2]=t4.z; v[q*4+3]=t4.w;
        }
        float mx = v[0];
        #pragma unroll
        for (int k = 1; k < 16; k++) mx = fmaxf(mx, v[k]);
        mx = fmaxf(mx, __shfl_xor(mx, 1));
        mx = fmaxf(mx, __shfl_xor(mx, 2));
        float z = 0.f;
        #pragma unroll
        for (int k = 0; k < 16; k++) { v[k] = __expf(v[k]-mx); z += v[k]; }
        z += __shfl_xor(z, 1);
        z += __shfl_xor(z, 2);
        const float inv = 1.0f / z;
        const float e0r = pE[r], dr = pE[64+r] - pE[r];
        __hip_bfloat16* Tp  = (__hip_bfloat16*)(SM + PT_T);
        __hip_bfloat16* Vt0 = (__hip_bfloat16*)(SM + PT_VT0);
        __hip_bfloat16* VtD = (__hip_bfloat16*)(SM + PT_VTD);
        #pragma unroll
        for (int k = 0; k < 16; k++) {
            const int j = q4*16 + k;
            const float t = v[k] * inv;
            Tp [r*MSTR + j] = __float2bfloat16(t);
            Vt0[j*MSTR + r] = __float2bfloat16(e0r * t);
            VtD[j*MSTR + r] = __float2bfloat16(dr  * t);
        }
    }
    __syncthreads();

    // phase 2: W_x = T * V_x (x in {0,D}), store plain
    #pragma unroll
    for (int xw = 0; xw < 2; xw++) {
        const __hip_bfloat16* A = (const __hip_bfloat16*)(SM + PT_T);
        const __hip_bfloat16* B = (const __hip_bfloat16*)(SM + (xw ? PT_VTD : PT_VT0));
        __hip_bfloat16* W = (__hip_bfloat16*)(SM + (xw ? PT_WPD : PT_WP0));
        #pragma unroll
        for (int tt = 0; tt < 4; tt++) {
            const int t8 = wv*4 + tt, xt = t8 >> 2, yb = t8 & 3;
            const bf16x8 a0 = *(const bf16x8*)(A + (xt*16+lr)*MSTR + g*8);
            const bf16x8 a1 = *(const bf16x8*)(A + (xt*16+lr)*MSTR + 32 + g*8);
            const bf16x8 b0 = *(const bf16x8*)(B + (yb*16+lr)*MSTR + g*8);
            const bf16x8 b1 = *(const bf16x8*)(B + (yb*16+lr)*MSTR + 32 + g*8);
            f32x4 d = MFMA(a0, b0, zero);
            d = MFMA(a1, b1, d);
            const int ycol = yb*16 + lr, xb = xt*16 + g*4;
            W[(xb+0)*MSTR + ycol] = __float2bfloat16(d.x);
            W[(xb+1)*MSTR + ycol] = __float2bfloat16(d.y);
            W[(xb+2)*MSTR + ycol] = __float2bfloat16(d.z);
            W[(xb+3)*MSTR + ycol] = __float2bfloat16(d.w);
        }
    }
    __syncthreads();

    // phase 3: C3_{sa,sb} = W_sa * V_sb -> ws, plain + transposed
    // basis index mm: bit1 = slot1(a), bit0 = slot2(b)   [verified R8 mapping]
    __hip_bfloat16* gC3p = (__hip_bfloat16*)(ws + WS_C3P);
    __hip_bfloat16* gC3t = (__hip_bfloat16*)(ws + WS_C3T);
    for (int mm = 0; mm < 4; mm++) {
        const int sa = mm >> 1, sb = mm & 1;
        const __hip_bfloat16* A = (const __hip_bfloat16*)(SM + (sa ? PT_WPD : PT_WP0));
        const __hip_bfloat16* B = (const __hip_bfloat16*)(SM + (sb ? PT_VTD : PT_VT0));
        #pragma unroll
        for (int tt = 0; tt < 4; tt++) {
            const int t8 = wv*4 + tt, xt = t8 >> 2, yb = t8 & 3;
            const bf16x8 a0 = *(const bf16x8*)(A + (xt*16+lr)*MSTR + g*8);
            const bf16x8 a1 = *(const bf16x8*)(A + (xt*16+lr)*MSTR + 32 + g*8);
            const bf16x8 b0 = *(const bf16x8*)(B + (yb*16+lr)*MSTR + g*8);
            const bf16x8 b1 = *(const bf16x8*)(B + (yb*16+lr)*MSTR + 32 + g*8);
            f32x4 d = MFMA(a0, b0, zero);
            d = MFMA(a1, b1, d);
            const int ycol = yb*16 + lr, xb = xt*16 + g*4;
            gC3p[mm*4096 + (xb+0)*64 + ycol] = __float2bfloat16(d.x);
            gC3p[mm*4096 + (xb+1)*64 + ycol] = __float2bfloat16(d.y);
            gC3p[mm*4096 + (xb+2)*64 + ycol] = __float2bfloat16(d.z);
            gC3p[mm*4096 + (xb+3)*64 + ycol] = __float2bfloat16(d.w);
            union { __hip_bfloat16 hh[4]; uint2 u; } pk;
            pk.hh[0] = __float2bfloat16(d.x);
            pk.hh[1] = __float2bfloat16(d.y);
            pk.hh[2] = __float2bfloat16(d.z);
            pk.hh[3] = __float2bfloat16(d.w);
            *(uint2*)(gC3t + mm*4096 + ycol*64 + xb) = pk.u;
        }
    }
}

// ---- main-kernel LDS (bytes) ----
#define MK_PF  0        // bf16 Pf[16][PSTR] = 2304 (fwd alpha, single buffer)
#define MK_PB  2304     // bf16 Pb[16][PSTR] = 2304 (bwd gamma)
#define MK_YSF 4608     // u64 ysf[11][16] = 1408
#define MK_YSB 6016     // u64 ysb[11][16] = 1408
#define MK_YB  7424     // u64 yball[16][16] = 2048
#define MK_LF  9472     // f32 laccF[16] = 64
#define MAIN_SZ 9536

// ---------------------------------------------------------------------------
// Main: 256 wgs x 128 thr. Wave 0 = fwd chain, wave 1 = bwd chain for the
// same 16-batch block. Each wave does the FULL 64-state k3 update per iter:
// 32 MFMAs (4 bases x 4 tiles x 2 K-halves, 128 VGPR of A-frags), multilinear
// combine (3 fmac/tile), tail emission, wave-local renorm every 4th iter.
// Single wave-private LDS alpha buffer, in-order DS => ZERO barriers in loop.
// Epilogue: in-wg dot of alpha_513 . beta_513.
// ---------------------------------------------------------------------------
__global__ __launch_bounds__(128, 1) void hmm_main(
    const int* __restrict__ y, const unsigned char* __restrict__ ws,
    float* __restrict__ out)
{
    __shared__ __align__(16) unsigned char SM[MAIN_SZ];
    const int tid  = threadIdx.x;
    const int wv   = tid >> 6;          // 0 = fwd, 1 = bwd
    const int lane = tid & 63;
    const int lr   = lane & 15;         // batch col within block
    const int g    = lane >> 4;         // k-group / state quad
    const int R0   = blockIdx.x * 16;
    const bool is_fwd = (wv == 0);
    const f32x4 zero = {0.f, 0.f, 0.f, 0.f};

    // A-frags: 4 bases x 4 state tiles x 2 K-halves (fwd transposed, bwd plain)
    bf16x8 Afr[4][4][2];
    {
        const __hip_bfloat16* Ab = (const __hip_bfloat16*)(ws + (is_fwd ? WS_C3T : WS_C3P));
        #pragma unroll
        for (int m = 0; m < 4; m++)
            #pragma unroll
            for (int t = 0; t < 4; t++) {
                Afr[m][t][0] = *(const bf16x8*)(Ab + m*4096 + (t*16+lr)*64 + g*8);
                Afr[m][t][1] = *(const bf16x8*)(Ab + m*4096 + (t*16+lr)*64 + 32 + g*8);
            }
    }
    // emission vectors for this lane's states t*16+g*4..+3
    const float* pE = (const float*)(ws + WS_PE);
    f32x4 E0v[4], E1v[4];
    #pragma unroll
    for (int t = 0; t < 4; t++) {
        E0v[t] = *(const f32x4*)(pE + t*16 + g*4);
        E1v[t] = *(const f32x4*)(pE + 64 + t*16 + g*4);
    }

    // ballot-pack y: wave wv packs rows wv*8 .. wv*8+7
    unsigned long long* yball = (unsigned long long*)(SM + MK_YB);
    #pragma unroll
    for (int q = 0; q < 8; q++) {
        const int row = wv*8 + q;
        const int* yr = y + (size_t)(R0 + row) * TLEN;
        #pragma unroll
        for (int w = 0; w < 16; w++) {
            const unsigned long long bal = __ballot(yr[w*64 + lane] != 0);
            if (lane == 0) yball[row*16 + w] = bal;
        }
    }
    __syncthreads();

    // nibble streams (bit0=a slot1, bit1=b slot2, bit2=tail):
    // fwd j: s=3j+1: a=y[s], b=y[s+1], tail=y[s+2]
    // bwd j: s=1020-3j: a=y[s+1], b=y[s+2], tail=y[s]  (j=169 = peel nibble)
    unsigned long long* ys = (unsigned long long*)(SM + (is_fwd ? MK_YSF : MK_YSB));
    {
        const int c = lane & 15;
        #pragma unroll
        for (int pass = 0; pass < 3; pass++) {
            const int slot = pass*4 + (lane >> 4);
            if (slot < 11) {
                unsigned long long wd = 0ull;
                for (int n = 0; n < 16; n++) {
                    const int j = slot*16 + n;
                    unsigned long long nib = 0ull;
                    if (is_fwd) {
                        if (j < NF_IT) {
                            const int s = 3*j + 1;
                            const unsigned long long bA = (yball[c*16 + ((s  )>>6)] >> ((s  ) & 63)) & 1ull;
                            const unsigned long long bB = (yball[c*16 + ((s+1)>>6)] >> ((s+1) & 63)) & 1ull;
                            const unsigned long long bT = (yball[c*16 + ((s+2)>>6)] >> ((s+2) & 63)) & 1ull;
                            nib = bA | (bB<<1) | (bT<<2);
                        }
                    } else {
                        if (j < NB_IT) {
                            const int s = 1020 - 3*j;
                            const unsigned long long bA = (yball[c*16 + ((s+1)>>6)] >> ((s+1) & 63)) & 1ull;
                            const unsigned long long bB = (yball[c*16 + ((s+2)>>6)] >> ((s+2) & 63)) & 1ull;
                            const unsigned long long bT = (yball[c*16 + ((s  )>>6)] >> ((s  ) & 63)) & 1ull;
                            nib = bA | (bB<<1) | (bT<<2);
                        }
                    }
                    wd |= nib << (4*n);
                }
                ys[slot*16 + c] = wd;
            }
        }
    }

    // init wave-private P + initial column sum Sw (wave-local only)
    __hip_bfloat16* P = (__hip_bfloat16*)(SM + (is_fwd ? MK_PF : MK_PB));
    float Sw;
    {
        float part = 0.f;
        if (is_fwd) {
            const int y0 = (int)(yball[lr*16] & 1ull);
            const float* pv = (const float*)(ws + WS_PIV);
            #pragma unroll
            for (int q = 0; q < 4; q++) {
                union { __hip_bfloat16 h[4]; uint2 u; } pk;
                #pragma unroll
                for (int r2 = 0; r2 < 4; r2++) {
                    const int s = g*16 + q*4 + r2;
                    const float v = pv[s] * pE[y0*64 + s];
                    pk.h[r2] = __float2bfloat16(v);
                    part += v;
                }
                *(uint2*)(P + lr*PSTR + g*16 + q*4) = pk.u;
            }
        } else {
            const int yl = (int)((yball[lr*16 + 15] >> 63) & 1ull);
            #pragma unroll
            for (int q = 0; q < 4; q++) {
                union { __hip_bfloat16 h[4]; uint2 u; } pk;
                #pragma unroll
                for (int r2 = 0; r2 < 4; r2++) {
                    const int s = g*16 + q*4 + r2;
                    const float v = pE[yl*64 + s];
                    pk.h[r2] = __float2bfloat16(v);
                    part += v;
                }
                *(uint2*)(P + lr*PSTR + g*16 + q*4) = pk.u;
            }
        }
        part += __shfl_xor(part, 16);
        part += __shfl_xor(part, 32);
        Sw = part;
    }

    // ---- barrier-free main loop ----
    float lacc = 0.f;
    unsigned long long yw = 0ull;
    const int nit = is_fwd ? NF_IT : (NB_IT - 1);   // bwd: 169 tailed iters

    for (int j = 0; j < nit; j++) {
        if ((j & 15) == 0) yw = ys[(j>>4)*16 + lr];
        const int nib = (int)(yw & 7ull);
        yw >>= 4;

        const bf16x8 B0 = *(const bf16x8*)(P + lr*PSTR + g*8);
        const bf16x8 B1 = *(const bf16x8*)(P + lr*PSTR + 32 + g*8);

        f32x4 dd[4][4];
        #pragma unroll
        for (int m = 0; m < 4; m++)
            #pragma unroll
            for (int t = 0; t < 4; t++)
                dd[m][t] = MFMA(Afr[m][t][0], B0, zero);
        #pragma unroll
        for (int m = 0; m < 4; m++)
            #pragma unroll
            for (int t = 0; t < 4; t++)
                dd[m][t] = MFMA(Afr[m][t][1], B1, dd[m][t]);

        const float fa  = (nib & 1) ? 1.0f : 0.0f;
        const float fb  = (nib & 2) ? 1.0f : 0.0f;
        const float fab = fa * fb;
        const int   tb  = (nib >> 2) & 1;

        float rs = 1.0f;
        if ((j & 3) == 0 && j > 0) {
            lacc += __logf(Sw);
            rs = __builtin_amdgcn_rcpf(Sw);
        }

        f32x4 val[4];
        #pragma unroll
        for (int t = 0; t < 4; t++) {
            f32x4 Dn = dd[0][t];
            Dn += fb  * dd[1][t];
            Dn += fa  * dd[2][t];
            Dn += fab * dd[3][t];
            const f32x4 ev = tb ? E1v[t] : E0v[t];
            val[t] = Dn * ev * rs;
        }

        if ((j & 3) == 3) {
            float p = 0.f;
            #pragma unroll
            for (int t = 0; t < 4; t++)
                p += val[t].x + val[t].y + val[t].z + val[t].w;
            p += __shfl_xor(p, 16);
            p += __shfl_xor(p, 32);
            Sw = p;
        }

        #pragma unroll
        for (int t = 0; t < 4; t++) {
            union { __hip_bfloat16 h[4]; uint2 u; } pk;
            pk.h[0] = __float2bfloat16(val[t].x);
            pk.h[1] = __float2bfloat16(val[t].y);
            pk.h[2] = __float2bfloat16(val[t].z);
            pk.h[3] = __float2bfloat16(val[t].w);
            *(uint2*)(P + lr*PSTR + t*16 + g*4) = pk.u;
        }
    }

    // ---- epilogue ----
    if (is_fwd) {
        if (g == 0) ((float*)(SM + MK_LF))[lr] = lacc;   // lacc uniform over g
        __syncthreads();
        // done; bwd wave produces the output
    } else {
        // peel: tail-less C3(a=y514, b=y515) -> beta_513 (in registers)
        const int nib = (int)(yw & 7ull);
        const bf16x8 B0 = *(const bf16x8*)(P + lr*PSTR + g*8);
        const bf16x8 B1 = *(const bf16x8*)(P + lr*PSTR + 32 + g*8);
        f32x4 dd[4][4];
        #pragma unroll
        for (int m = 0; m < 4; m++)
            #pragma unroll
            for (int t = 0; t < 4; t++)
                dd[m][t] = MFMA(Afr[m][t][0], B0, zero);
        #pragma unroll
        for (int m = 0; m < 4; m++)
            #pragma unroll
            for (int t = 0; t < 4; t++)
                dd[m][t] = MFMA(Afr[m][t][1], B1, dd[m][t]);
        const float fa  = (nib & 1) ? 1.0f : 0.0f;
        const float fb  = (nib & 2) ? 1.0f : 0.0f;
        const float fab = fa * fb;
        f32x4 val[4];
        #pragma unroll
        for (int t = 0; t < 4; t++) {
            f32x4 Dn = dd[0][t];
            Dn += fb  * dd[1][t];
            Dn += fa  * dd[2][t];
            Dn += fab * dd[3][t];
            val[t] = Dn;     // no tail, no renorm (residual absorbed in log-dot)
        }
        __syncthreads();
        // dot: alpha_513 (Pf, bf16) . beta_513 (regs), per batch col lr
        const __hip_bfloat16* Pf = (const __hip_bfloat16*)(SM + MK_PF);
        float dot = 0.f;
        #pragma unroll
        for (int t = 0; t < 4; t++) {
            union { uint2 u; __hip_bfloat16 h[4]; } ua;
            ua.u = *(const uint2*)(Pf + lr*PSTR + t*16 + g*4);
            dot += __bfloat162float(ua.h[0]) * val[t].x
                 + __bfloat162float(ua.h[1]) * val[t].y
                 + __bfloat162float(ua.h[2]) * val[t].z
                 + __bfloat162float(ua.h[3]) * val[t].w;
        }
        dot += __shfl_xor(dot, 16);
        dot += __shfl_xor(dot, 32);
        float lp = lacc + ((float*)(SM + MK_LF))[lr] + __logf(dot);
        if (g == 0) {                    // lanes 0..15, one per batch row
            lp += __shfl_xor(lp, 1);
            lp += __shfl_xor(lp, 2);
            lp += __shfl_xor(lp, 4);
            lp += __shfl_xor(lp, 8);
            if (lr == 0) atomicAdd(out, lp * (1.0f / BATCH));
        }
    }
}

// ---------------------------------------------------------------------------
extern "C" void kernel_launch(void* const* d_in, const int* in_sizes, int n_in,
                              void* d_out, int out_size, void* d_ws, size_t ws_size,
                              hipStream_t stream) {
    const int*   y  = (const int*)  d_in[0];
    const float* T  = (const float*)d_in[1];
    const float* E  = (const float*)d_in[2];
    const float* Pi = (const float*)d_in[3];
    float* out = (float*)d_out;
    unsigned char* ws = (unsigned char*)d_ws;
    (void)ws_size;

    hipLaunchKernelGGL(hmm_pre,  dim3(1),        dim3(256), 0, stream, T, E, Pi, ws, out);
    hipLaunchKernelGGL(hmm_main, dim3(BATCH/16), dim3(128), 0, stream, y, ws, out);
}